// Round 5
// baseline (91.288 us; speedup 1.0000x reference)
//
#include <hip/hip_runtime.h>

#define ORDER 8
#define FDIM 4096
#define NROWS 8192
#define THREADS 256
#define RPB 4            // rows of x per block
#define F4T 4            // float4 chunks per thread per row: 4096/4/256
#define F4DIM (FDIM/4)   // 1024 float4s per row
#define NPAIR 36         // upper-triangular pairs of 8

typedef float fvec4 __attribute__((ext_vector_type(4)));  // native vec: nontemporal-ok

// ---------------------------------------------------------------------------
// Prep: reparameterize v, d, bias; normalize v rows.
// blocks 0..7 -> vn row b ; block 8 -> d ; block 9 -> bias
// ---------------------------------------------------------------------------
__global__ __launch_bounds__(THREADS) void obd_prep(
    const float* __restrict__ v_mean, const float* __restrict__ v_logvar,
    const float* __restrict__ eps_v,
    const float* __restrict__ d_mean, const float* __restrict__ d_logvar,
    const float* __restrict__ eps_d,
    const float* __restrict__ b_mean, const float* __restrict__ b_logvar,
    const float* __restrict__ eps_b,
    float* __restrict__ vn, float* __restrict__ dsc, float* __restrict__ bias)
{
    const int b = blockIdx.x;
    const int t = threadIdx.x;
    __shared__ float red[THREADS / 64];

    if (b < ORDER) {
        const fvec4* vm = (const fvec4*)(v_mean   + (size_t)b * FDIM);
        const fvec4* vl = (const fvec4*)(v_logvar + (size_t)b * FDIM);
        const fvec4* ev = (const fvec4*)(eps_v    + (size_t)b * FDIM);
        fvec4 val[F4T];
        float ss = 0.f;
        #pragma unroll
        for (int k = 0; k < F4T; ++k) {
            const int idx = t + k * THREADS;
            fvec4 m = vm[idx], l = vl[idx], e = ev[idx];
            fvec4 v;
            #pragma unroll
            for (int c = 0; c < 4; ++c)
                v[c] = fmaf(expf(0.5f * l[c]), e[c], m[c]);
            val[k] = v;
            ss += v[0]*v[0] + v[1]*v[1] + v[2]*v[2] + v[3]*v[3];
        }
        #pragma unroll
        for (int off = 32; off; off >>= 1) ss += __shfl_down(ss, off);
        const int wave = t >> 6, lane = t & 63;
        if (lane == 0) red[wave] = ss;
        __syncthreads();
        const float inv = 1.0f / sqrtf(red[0] + red[1] + red[2] + red[3]);
        fvec4* vno = (fvec4*)(vn + (size_t)b * FDIM);
        #pragma unroll
        for (int k = 0; k < F4T; ++k) {
            const int idx = t + k * THREADS;
            vno[idx] = val[k] * inv;
        }
    } else if (b == ORDER) {
        #pragma unroll
        for (int k = 0; k < 16; ++k) {
            const int idx = t + k * THREADS;
            dsc[idx] = fmaf(expf(0.5f * d_logvar[idx]), eps_d[idx], d_mean[idx]);
        }
    } else {
        #pragma unroll
        for (int k = 0; k < 16; ++k) {
            const int idx = t + k * THREADS;
            bias[idx] = fmaf(expf(0.5f * b_logvar[idx]), eps_b[idx], b_mean[idx]);
        }
    }
}

// ---------------------------------------------------------------------------
// Gram + T: single block. G[i][j] = vn_i . vn_j (i<=j); compact-WY factor:
// T[0][0]=2; col j: T[i][j] = -2 * sum_{m<j} T[i][m]G[m][j], T[j][j]=2.
// H0..H7 = I - V T V^T.
// ---------------------------------------------------------------------------
__global__ __launch_bounds__(THREADS) void obd_gramT(
    const float* __restrict__ vn, float* __restrict__ Tm)
{
    const int t = threadIdx.x;
    const int wave = t >> 6, lane = t & 63;
    const fvec4* Vv = (const fvec4*)vn;

    float acc[ORDER][ORDER];
    #pragma unroll
    for (int i = 0; i < ORDER; ++i)
        #pragma unroll
        for (int j = i; j < ORDER; ++j) acc[i][j] = 0.f;

    #pragma unroll
    for (int k = 0; k < F4T; ++k) {
        const int idx = t + k * THREADS;
        fvec4 vc[ORDER];
        #pragma unroll
        for (int i = 0; i < ORDER; ++i) vc[i] = Vv[i * F4DIM + idx];
        #pragma unroll
        for (int i = 0; i < ORDER; ++i)
            #pragma unroll
            for (int j = i; j < ORDER; ++j)
                #pragma unroll
                for (int c = 0; c < 4; ++c)
                    acc[i][j] = fmaf(vc[i][c], vc[j][c], acc[i][j]);
    }
    #pragma unroll
    for (int off = 32; off; off >>= 1)
        #pragma unroll
        for (int i = 0; i < ORDER; ++i)
            #pragma unroll
            for (int j = i; j < ORDER; ++j)
                acc[i][j] += __shfl_down(acc[i][j], off);

    __shared__ float red[THREADS / 64][NPAIR];
    if (lane == 0) {
        int p = 0;
        #pragma unroll
        for (int i = 0; i < ORDER; ++i)
            #pragma unroll
            for (int j = i; j < ORDER; ++j) red[wave][p++] = acc[i][j];
    }
    __syncthreads();
    if (t == 0) {
        float G[ORDER][ORDER];
        int p = 0;
        for (int i = 0; i < ORDER; ++i)
            for (int j = i; j < ORDER; ++j) {
                G[i][j] = red[0][p] + red[1][p] + red[2][p] + red[3][p];
                ++p;
            }
        float T[ORDER][ORDER];
        for (int i = 0; i < ORDER; ++i)
            for (int j = 0; j < ORDER; ++j) T[i][j] = 0.f;
        T[0][0] = 2.f;
        for (int j = 1; j < ORDER; ++j) {
            for (int i = 0; i < j; ++i) {
                float s = 0.f;
                for (int m = i; m < j; ++m) s += T[i][m] * G[m][j];
                T[i][j] = -2.f * s;
            }
            T[j][j] = 2.f;
        }
        for (int i = 0; i < ORDER; ++i)
            for (int j = 0; j < ORDER; ++j) Tm[i * ORDER + j] = T[i][j];
    }
}

// ---------------------------------------------------------------------------
// Main (compact WY, transient x): x is NOT held across the barrier — pass 2
// re-reads it (block's 64 KB slice is L2-resident from pass 1). Cuts VGPR
// from 128 (4 waves/SIMD) to ~80 (6 waves/SIMD) and shortens the per-wave
// dependency chain; occupancy was the binding constraint in R3 (19.5%).
//   pass 1: p[rr][i] = row_rr . v_i   (transient x loads)
//   q = p @ T  (8x8 upper-tri from LDS)
//   pass 2: out = (x - sum_j q[j] v_j) * d + bias   (x reloaded, nt-store)
// ---------------------------------------------------------------------------
__global__ __launch_bounds__(THREADS) void obd_wy(
    const float* __restrict__ x, const float* __restrict__ vn,
    const float* __restrict__ Tm, const float* __restrict__ dsc,
    const float* __restrict__ bias, float* __restrict__ out)
{
    const int t = threadIdx.x;
    const int wave = t >> 6, lane = t & 63;
    const size_t row0 = (size_t)blockIdx.x * RPB;
    const fvec4* xv = (const fvec4*)x;
    const fvec4* Vv = (const fvec4*)vn;
    fvec4* ov = (fvec4*)out;

    __shared__ float Ts[64];
    __shared__ float red[THREADS / 64][RPB * ORDER];
    if (t < 64) Ts[t] = Tm[t];

    // Pass 1: all 8 dots per row, x chunks transient.
    float p[RPB][ORDER];
    #pragma unroll
    for (int rr = 0; rr < RPB; ++rr)
        #pragma unroll
        for (int i = 0; i < ORDER; ++i) p[rr][i] = 0.f;

    #pragma unroll
    for (int k = 0; k < F4T; ++k) {
        const int idx = t + k * THREADS;
        fvec4 xr[RPB];
        #pragma unroll
        for (int rr = 0; rr < RPB; ++rr)
            xr[rr] = xv[(row0 + rr) * F4DIM + idx];
        #pragma unroll
        for (int i = 0; i < ORDER; ++i) {
            const fvec4 vc = Vv[i * F4DIM + idx];
            #pragma unroll
            for (int rr = 0; rr < RPB; ++rr)
                #pragma unroll
                for (int c = 0; c < 4; ++c)
                    p[rr][i] = fmaf(xr[rr][c], vc[c], p[rr][i]);
        }
    }
    #pragma unroll
    for (int off = 32; off; off >>= 1)
        #pragma unroll
        for (int rr = 0; rr < RPB; ++rr)
            #pragma unroll
            for (int i = 0; i < ORDER; ++i)
                p[rr][i] += __shfl_down(p[rr][i], off);
    if (lane == 0) {
        #pragma unroll
        for (int rr = 0; rr < RPB; ++rr)
            #pragma unroll
            for (int i = 0; i < ORDER; ++i)
                red[wave][rr * ORDER + i] = p[rr][i];
    }
    __syncthreads();  // also covers the Ts staging load

    // q = p @ T  (negated for the fma update)
    float mq[RPB][ORDER];
    #pragma unroll
    for (int rr = 0; rr < RPB; ++rr) {
        float dot[ORDER];
        #pragma unroll
        for (int i = 0; i < ORDER; ++i)
            dot[i] = red[0][rr * ORDER + i] + red[1][rr * ORDER + i]
                   + red[2][rr * ORDER + i] + red[3][rr * ORDER + i];
        #pragma unroll
        for (int j = 0; j < ORDER; ++j) {
            float s = 0.f;
            #pragma unroll
            for (int i = 0; i <= j; ++i) s = fmaf(dot[i], Ts[i * ORDER + j], s);
            mq[rr][j] = -s;
        }
    }

    // Pass 2: reload x (L2-hot), rank-8 update, fused epilogue, nt store.
    const fvec4* dv = (const fvec4*)dsc;
    const fvec4* bv = (const fvec4*)bias;
    #pragma unroll
    for (int k = 0; k < F4T; ++k) {
        const int idx = t + k * THREADS;
        fvec4 acc[RPB];
        #pragma unroll
        for (int rr = 0; rr < RPB; ++rr)
            acc[rr] = xv[(row0 + rr) * F4DIM + idx];
        #pragma unroll
        for (int i = 0; i < ORDER; ++i) {
            const fvec4 vc = Vv[i * F4DIM + idx];
            #pragma unroll
            for (int rr = 0; rr < RPB; ++rr)
                #pragma unroll
                for (int c = 0; c < 4; ++c)
                    acc[rr][c] = fmaf(mq[rr][i], vc[c], acc[rr][c]);
        }
        const fvec4 dd = dv[idx];
        const fvec4 bb = bv[idx];
        #pragma unroll
        for (int rr = 0; rr < RPB; ++rr) {
            fvec4 o;
            #pragma unroll
            for (int c = 0; c < 4; ++c)
                o[c] = fmaf(acc[rr][c], dd[c], bb[c]);
            __builtin_nontemporal_store(o, &ov[(row0 + rr) * F4DIM + idx]);
        }
    }
}

extern "C" void kernel_launch(void* const* d_in, const int* in_sizes, int n_in,
                              void* d_out, int out_size, void* d_ws, size_t ws_size,
                              hipStream_t stream) {
    const float* x        = (const float*)d_in[0];
    const float* v_mean   = (const float*)d_in[1];
    const float* v_logvar = (const float*)d_in[2];
    const float* d_mean   = (const float*)d_in[3];
    const float* d_logvar = (const float*)d_in[4];
    const float* b_mean   = (const float*)d_in[5];
    const float* b_logvar = (const float*)d_in[6];
    const float* eps_v    = (const float*)d_in[7];
    const float* eps_d    = (const float*)d_in[8];
    const float* eps_b    = (const float*)d_in[9];

    float* ws   = (float*)d_ws;
    float* vn   = ws;                                  // 8*4096
    float* dsc  = ws + ORDER * FDIM;                   // 4096
    float* bias = ws + ORDER * FDIM + FDIM;            // 4096
    float* Tm   = ws + ORDER * FDIM + 2 * FDIM;        // 64

    obd_prep<<<ORDER + 2, THREADS, 0, stream>>>(
        v_mean, v_logvar, eps_v, d_mean, d_logvar, eps_d,
        b_mean, b_logvar, eps_b, vn, dsc, bias);
    obd_gramT<<<1, THREADS, 0, stream>>>(vn, Tm);
    obd_wy<<<NROWS / RPB, THREADS, 0, stream>>>(
        x, vn, Tm, dsc, bias, (float*)d_out);
}

// Round 6
// 86.560 us; speedup vs baseline: 1.0546x; 1.0546x over previous
//
#include <hip/hip_runtime.h>

#define ORDER 8
#define FDIM 4096
#define NROWS 8192
#define THREADS 256
#define F4T 4            // fvec4 chunks per thread (prep/gram): 4096/4/256
#define F4DIM (FDIM/4)   // 1024 fvec4 per row
#define NPAIR 36         // upper-triangular pairs of 8

typedef float fvec4 __attribute__((ext_vector_type(4)));

// ---------------------------------------------------------------------------
// Prep: reparameterize v, d, bias; normalize v rows.
// blocks 0..7 -> vn row b ; block 8 -> d ; block 9 -> bias
// ---------------------------------------------------------------------------
__global__ __launch_bounds__(THREADS) void obd_prep(
    const float* __restrict__ v_mean, const float* __restrict__ v_logvar,
    const float* __restrict__ eps_v,
    const float* __restrict__ d_mean, const float* __restrict__ d_logvar,
    const float* __restrict__ eps_d,
    const float* __restrict__ b_mean, const float* __restrict__ b_logvar,
    const float* __restrict__ eps_b,
    float* __restrict__ vn, float* __restrict__ dsc, float* __restrict__ bias)
{
    const int b = blockIdx.x;
    const int t = threadIdx.x;
    __shared__ float red[THREADS / 64];

    if (b < ORDER) {
        const fvec4* vm = (const fvec4*)(v_mean   + (size_t)b * FDIM);
        const fvec4* vl = (const fvec4*)(v_logvar + (size_t)b * FDIM);
        const fvec4* ev = (const fvec4*)(eps_v    + (size_t)b * FDIM);
        fvec4 val[F4T];
        float ss = 0.f;
        #pragma unroll
        for (int k = 0; k < F4T; ++k) {
            const int idx = t + k * THREADS;
            fvec4 m = vm[idx], l = vl[idx], e = ev[idx];
            fvec4 v;
            #pragma unroll
            for (int c = 0; c < 4; ++c)
                v[c] = fmaf(expf(0.5f * l[c]), e[c], m[c]);
            val[k] = v;
            ss += v[0]*v[0] + v[1]*v[1] + v[2]*v[2] + v[3]*v[3];
        }
        #pragma unroll
        for (int off = 32; off; off >>= 1) ss += __shfl_down(ss, off);
        const int wave = t >> 6, lane = t & 63;
        if (lane == 0) red[wave] = ss;
        __syncthreads();
        const float inv = 1.0f / sqrtf(red[0] + red[1] + red[2] + red[3]);
        fvec4* vno = (fvec4*)(vn + (size_t)b * FDIM);
        #pragma unroll
        for (int k = 0; k < F4T; ++k)
            vno[t + k * THREADS] = val[k] * inv;
    } else if (b == ORDER) {
        #pragma unroll
        for (int k = 0; k < 16; ++k) {
            const int idx = t + k * THREADS;
            dsc[idx] = fmaf(expf(0.5f * d_logvar[idx]), eps_d[idx], d_mean[idx]);
        }
    } else {
        #pragma unroll
        for (int k = 0; k < 16; ++k) {
            const int idx = t + k * THREADS;
            bias[idx] = fmaf(expf(0.5f * b_logvar[idx]), eps_b[idx], b_mean[idx]);
        }
    }
}

// ---------------------------------------------------------------------------
// Gram + T + Md: single block.
//   G[i][j] = vn_i . vn_j  (block reduce)
//   T: compact-WY factor (thread 0): H0..H7 = I - V^T T V
//   Md[i][c] = -(T V)[i][c] * d[c]   -> the rank-8 update matrix for kernel B
// ---------------------------------------------------------------------------
__global__ __launch_bounds__(THREADS) void obd_gramT(
    const float* __restrict__ vn, const float* __restrict__ dsc,
    float* __restrict__ Md)
{
    const int t = threadIdx.x;
    const int wave = t >> 6, lane = t & 63;
    const fvec4* Vv = (const fvec4*)vn;

    float acc[ORDER][ORDER];
    #pragma unroll
    for (int i = 0; i < ORDER; ++i)
        #pragma unroll
        for (int j = i; j < ORDER; ++j) acc[i][j] = 0.f;

    #pragma unroll
    for (int k = 0; k < F4T; ++k) {
        const int idx = t + k * THREADS;
        fvec4 vc[ORDER];
        #pragma unroll
        for (int i = 0; i < ORDER; ++i) vc[i] = Vv[i * F4DIM + idx];
        #pragma unroll
        for (int i = 0; i < ORDER; ++i)
            #pragma unroll
            for (int j = i; j < ORDER; ++j)
                #pragma unroll
                for (int c = 0; c < 4; ++c)
                    acc[i][j] = fmaf(vc[i][c], vc[j][c], acc[i][j]);
    }
    #pragma unroll
    for (int off = 32; off; off >>= 1)
        #pragma unroll
        for (int i = 0; i < ORDER; ++i)
            #pragma unroll
            for (int j = i; j < ORDER; ++j)
                acc[i][j] += __shfl_down(acc[i][j], off);

    __shared__ float red[THREADS / 64][NPAIR];
    __shared__ float Tsh[ORDER * ORDER];
    if (lane == 0) {
        int p = 0;
        #pragma unroll
        for (int i = 0; i < ORDER; ++i)
            #pragma unroll
            for (int j = i; j < ORDER; ++j) red[wave][p++] = acc[i][j];
    }
    __syncthreads();
    if (t == 0) {
        float G[ORDER][ORDER];
        int p = 0;
        for (int i = 0; i < ORDER; ++i)
            for (int j = i; j < ORDER; ++j) {
                G[i][j] = red[0][p] + red[1][p] + red[2][p] + red[3][p];
                ++p;
            }
        float T[ORDER][ORDER];
        for (int i = 0; i < ORDER; ++i)
            for (int j = 0; j < ORDER; ++j) T[i][j] = 0.f;
        T[0][0] = 2.f;
        for (int j = 1; j < ORDER; ++j) {
            for (int i = 0; i < j; ++i) {
                float s = 0.f;
                for (int m = i; m < j; ++m) s += T[i][m] * G[m][j];
                T[i][j] = -2.f * s;
            }
            T[j][j] = 2.f;
        }
        for (int i = 0; i < ORDER; ++i)
            for (int j = 0; j < ORDER; ++j) Tsh[i * ORDER + j] = T[i][j];
    }
    __syncthreads();

    // Md[i][c] = -(sum_{m>=i} T[i][m] * V[m][c]) * d[c]
    const fvec4* dv = (const fvec4*)dsc;
    fvec4* Mdv = (fvec4*)Md;
    #pragma unroll
    for (int k = 0; k < F4T; ++k) {
        const int idx = t + k * THREADS;
        fvec4 vcol[ORDER];
        #pragma unroll
        for (int m = 0; m < ORDER; ++m) vcol[m] = Vv[m * F4DIM + idx];
        const fvec4 dd = dv[idx];
        #pragma unroll
        for (int i = 0; i < ORDER; ++i) {
            fvec4 s = {0.f, 0.f, 0.f, 0.f};
            #pragma unroll
            for (int m = 0; m < ORDER; ++m) {
                if (m >= i) {
                    const float tv = Tsh[i * ORDER + m];
                    #pragma unroll
                    for (int c = 0; c < 4; ++c) s[c] = fmaf(tv, vcol[m][c], s[c]);
                }
            }
            Mdv[i * F4DIM + idx] = -(s * dd);
        }
    }
}

// ---------------------------------------------------------------------------
// Kernel A: P = x @ V^T   (8192 x 8). Wave-independent: each wave owns 2
// rows, sweeps 16 chunks (idx = it*64 + lane), butterfly-reduces 16 dots
// in-wave, lane 0 writes 16 floats. NO LDS, NO barrier, no second pass.
// ---------------------------------------------------------------------------
#define RPW 2            // rows per wave
__global__ __launch_bounds__(THREADS, 3) void obd_dots(
    const float* __restrict__ x, const float* __restrict__ vn,
    float* __restrict__ P)
{
    const int t = threadIdx.x;
    const int wave = t >> 6, lane = t & 63;
    const size_t r0 = ((size_t)blockIdx.x * 4 + wave) * RPW;
    const fvec4* xv = (const fvec4*)x;
    const fvec4* Vv = (const fvec4*)vn;

    float p[RPW][ORDER];
    #pragma unroll
    for (int rr = 0; rr < RPW; ++rr)
        #pragma unroll
        for (int i = 0; i < ORDER; ++i) p[rr][i] = 0.f;

    for (int it = 0; it < F4DIM / 64; ++it) {
        const int idx = it * 64 + lane;
        fvec4 xr[RPW];
        #pragma unroll
        for (int rr = 0; rr < RPW; ++rr)
            xr[rr] = xv[(r0 + rr) * F4DIM + idx];
        #pragma unroll
        for (int i = 0; i < ORDER; ++i) {
            const fvec4 vc = Vv[i * F4DIM + idx];
            #pragma unroll
            for (int rr = 0; rr < RPW; ++rr)
                #pragma unroll
                for (int c = 0; c < 4; ++c)
                    p[rr][i] = fmaf(xr[rr][c], vc[c], p[rr][i]);
        }
    }
    #pragma unroll
    for (int off = 32; off; off >>= 1)
        #pragma unroll
        for (int rr = 0; rr < RPW; ++rr)
            #pragma unroll
            for (int i = 0; i < ORDER; ++i)
                p[rr][i] += __shfl_down(p[rr][i], off);
    #pragma unroll
    for (int rr = 0; rr < RPW; ++rr)
        #pragma unroll
        for (int i = 0; i < ORDER; ++i) {
            const float v = p[rr][i];
            if (lane == 0) P[(r0 + rr) * ORDER + i] = v;
        }
}

// ---------------------------------------------------------------------------
// Kernel B: out = x*d + sum_i P[r][i]*Md[i] + bias. Column-stripe blocks:
// each block owns 1024 float columns; Md/d/bias slice lives in registers
// (loaded once), then 16 rows of pure streaming: load x (L3-hot) + P[r]
// (uniform -> scalar loads), 9 FMAs/vec, nontemporal store. No reduction,
// no barrier, no LDS.
// ---------------------------------------------------------------------------
#define BROWS 16         // rows per block
#define NSTRIPE (F4DIM / THREADS)   // 4 column stripes
__global__ __launch_bounds__(THREADS, 3) void obd_out(
    const float* __restrict__ x, const float* __restrict__ P,
    const float* __restrict__ Md, const float* __restrict__ dsc,
    const float* __restrict__ bias, float* __restrict__ out)
{
    const int t = threadIdx.x;
    const int stripe = blockIdx.x & (NSTRIPE - 1);
    const size_t rbase = (size_t)(blockIdx.x >> 2) * BROWS;
    const int cvec = stripe * THREADS + t;     // fvec4 column index

    const fvec4* xv  = (const fvec4*)x;
    const fvec4* Pv  = (const fvec4*)P;
    const fvec4* Mdv = (const fvec4*)Md;
    fvec4* ov        = (fvec4*)out;

    fvec4 md[ORDER];
    #pragma unroll
    for (int i = 0; i < ORDER; ++i) md[i] = Mdv[i * F4DIM + cvec];
    const fvec4 dd = ((const fvec4*)dsc)[cvec];
    const fvec4 bb = ((const fvec4*)bias)[cvec];

    for (int r = 0; r < BROWS; ++r) {
        const size_t row = rbase + r;
        const fvec4 xr = xv[row * F4DIM + cvec];
        const fvec4 P0 = Pv[row * 2];      // uniform across block -> s_load
        const fvec4 P1 = Pv[row * 2 + 1];
        fvec4 acc;
        #pragma unroll
        for (int c = 0; c < 4; ++c) acc[c] = fmaf(xr[c], dd[c], bb[c]);
        #pragma unroll
        for (int i = 0; i < 4; ++i)
            #pragma unroll
            for (int c = 0; c < 4; ++c)
                acc[c] = fmaf(P0[i], md[i][c], acc[c]);
        #pragma unroll
        for (int i = 0; i < 4; ++i)
            #pragma unroll
            for (int c = 0; c < 4; ++c)
                acc[c] = fmaf(P1[i], md[4 + i][c], acc[c]);
        __builtin_nontemporal_store(acc, &ov[row * F4DIM + cvec]);
    }
}

extern "C" void kernel_launch(void* const* d_in, const int* in_sizes, int n_in,
                              void* d_out, int out_size, void* d_ws, size_t ws_size,
                              hipStream_t stream) {
    const float* x        = (const float*)d_in[0];
    const float* v_mean   = (const float*)d_in[1];
    const float* v_logvar = (const float*)d_in[2];
    const float* d_mean   = (const float*)d_in[3];
    const float* d_logvar = (const float*)d_in[4];
    const float* b_mean   = (const float*)d_in[5];
    const float* b_logvar = (const float*)d_in[6];
    const float* eps_v    = (const float*)d_in[7];
    const float* eps_d    = (const float*)d_in[8];
    const float* eps_b    = (const float*)d_in[9];

    float* ws   = (float*)d_ws;
    float* vn   = ws;                        // 8*4096
    float* dsc  = vn + ORDER * FDIM;         // 4096
    float* bias = dsc + FDIM;                // 4096
    float* Md   = bias + FDIM;               // 8*4096
    float* P    = Md + ORDER * FDIM;         // 8192*8

    obd_prep<<<ORDER + 2, THREADS, 0, stream>>>(
        v_mean, v_logvar, eps_v, d_mean, d_logvar, eps_d,
        b_mean, b_logvar, eps_b, vn, dsc, bias);
    obd_gramT<<<1, THREADS, 0, stream>>>(vn, dsc, Md);
    obd_dots<<<NROWS / (RPW * 4), THREADS, 0, stream>>>(x, vn, P);
    obd_out<<<NSTRIPE * (NROWS / BROWS), THREADS, 0, stream>>>(
        x, P, Md, dsc, bias, (float*)d_out);
}